// Round 1
// baseline (379.869 us; speedup 1.0000x reference)
//
#include <hip/hip_runtime.h>

#define BATCH 8192
#define FEATURE_NUM 200
#define NUMERIC_SIZE 100
#define IN_STRIDE (FEATURE_NUM + NUMERIC_SIZE)  // 300
#define EMBED 64

// One wave (64 lanes) per batch row. lane = embedding dim e.
// fs/fss accumulate field_sum[e] / field_sq_sum[e] per lane.
// First-order gathers are distributed across lanes, then a single
// wave-wide shuffle reduction produces the scalar output.
__global__ __launch_bounds__(256) void fm_layer_kernel(
    const float* __restrict__ inputs,      // (B, 300)
    const float* __restrict__ w_one_hot,   // (1e6, 1)
    const float* __restrict__ w_numeric,   // (100, 1)
    const float* __restrict__ v_one_hot,   // (1e6, 64)
    const float* __restrict__ v_numeric,   // (100, 64)
    const float* __restrict__ bias,        // (1,)
    float* __restrict__ out)               // (B, 1)
{
    const int lane = threadIdx.x & 63;
    const int wave = threadIdx.x >> 6;
    const int row  = blockIdx.x * 4 + wave;
    if (row >= BATCH) return;

    const float* in_row = inputs + (size_t)row * IN_STRIDE;

    float fs  = 0.f;   // field_sum[lane]
    float fss = 0.f;   // field_sq_sum[lane]

    // ---- second-order: one-hot gathers (200 x 256B coalesced rows) ----
    #pragma unroll 8
    for (int j = 0; j < FEATURE_NUM; ++j) {
        // wave-uniform address -> scalar load path
        int idx = (int)in_row[j];
        float v = v_one_hot[(size_t)idx * EMBED + lane];
        fs  += v;
        fss += v * v;
    }

    // ---- second-order: numeric part (v_numeric is L1-resident, 25.6 KB) ----
    #pragma unroll 4
    for (int j = 0; j < NUMERIC_SIZE; ++j) {
        float x  = in_row[FEATURE_NUM + j];      // wave-uniform
        float v  = v_numeric[j * EMBED + lane];
        float nv = x * v;
        fs  += nv;
        fss += nv * nv;
    }

    // ---- first-order: distribute the 200 w_one_hot gathers over lanes ----
    float first = 0.f;
    #pragma unroll
    for (int j = lane; j < FEATURE_NUM; j += 64) {
        int idx = (int)in_row[j];                // per-lane -> vector gather
        first += w_one_hot[idx];
    }
    #pragma unroll
    for (int j = lane; j < NUMERIC_SIZE; j += 64) {
        first += in_row[FEATURE_NUM + j] * w_numeric[j];
    }

    // per-lane partial: first-order partial + FM identity term for e=lane
    float partial = first + 0.5f * (fs * fs - fss);

    // wave64 reduction
    #pragma unroll
    for (int off = 32; off > 0; off >>= 1)
        partial += __shfl_down(partial, off, 64);

    if (lane == 0) out[row] = partial + bias[0];
}

extern "C" void kernel_launch(void* const* d_in, const int* in_sizes, int n_in,
                              void* d_out, int out_size, void* d_ws, size_t ws_size,
                              hipStream_t stream) {
    const float* inputs    = (const float*)d_in[0];
    const float* w_one_hot = (const float*)d_in[1];
    const float* w_numeric = (const float*)d_in[2];
    const float* v_one_hot = (const float*)d_in[3];
    const float* v_numeric = (const float*)d_in[4];
    const float* bias      = (const float*)d_in[5];
    float* out = (float*)d_out;

    dim3 grid(BATCH / 4);   // 4 rows (waves) per 256-thread block
    dim3 block(256);
    fm_layer_kernel<<<grid, block, 0, stream>>>(
        inputs, w_one_hot, w_numeric, v_one_hot, v_numeric, bias, out);
}